// Round 2
// baseline (452.896 us; speedup 1.0000x reference)
//
#include <hip/hip_runtime.h>

// Problem constants (from reference): C=N=8192, F=64, B=128, S=1.
// out[b,n] = sum_{f<64} x[b,(n+f)&8191] * K[(n+f)&8191, n] + bias[n]
// All tensors fp32 (reference dtypes; R1 established harness is fp32 end-to-end).
#define C_DIM 8192
#define N_DIM 8192
#define F_DIM 64
#define B_DIM 128

__global__ __launch_bounds__(256) void cscfc_kernel(
    const float* __restrict__ x,     // (B, C)
    const float* __restrict__ K,     // (C, N)
    const float* __restrict__ bias,  // (N,)
    float* __restrict__ out)         // (B, N)
{
    const int n = blockIdx.x * 256 + threadIdx.x;   // output column
    const int b = blockIdx.y;                        // batch row

    const float* __restrict__ xb = x + (size_t)b * C_DIM;

    float acc = 0.0f;
#pragma unroll 16
    for (int f = 0; f < F_DIM; ++f) {
        const int c = (n + f) & (C_DIM - 1);         // (n+f) % C, C pow2
        acc = fmaf(xb[c], K[(size_t)c * N_DIM + n], acc);
    }
    acc += bias[n];
    out[(size_t)b * N_DIM + n] = acc;
}

extern "C" void kernel_launch(void* const* d_in, const int* in_sizes, int n_in,
                              void* d_out, int out_size, void* d_ws, size_t ws_size,
                              hipStream_t stream) {
    const float* x    = (const float*)d_in[0]; // (128, 8192)
    const float* K    = (const float*)d_in[1]; // (8192, 8192)
    const float* bias = (const float*)d_in[2]; // (8192,)
    float* out = (float*)d_out;                // (128, 8192)

    dim3 grid(N_DIM / 256, B_DIM, 1);  // (32, 128)
    dim3 block(256, 1, 1);
    cscfc_kernel<<<grid, block, 0, stream>>>(x, K, bias, out);
}

// Round 3
// 321.014 us; speedup vs baseline: 1.4108x; 1.4108x over previous
//
#include <hip/hip_runtime.h>

// out[b,n] = sum_{f<64} x[b,(n+f)&8191] * K[(n+f)&8191, n] + bias[n]
// fp32 end-to-end. B=128, C=N=8192, F=64.
//
// R2 postmortem: naive kernel was uncoalesced-VMEM bound (K diagonal access =
// 64 lines/instr). Fix: coalesced LDS staging of the K band (transposed to
// w_t[f][n]) + x window; register-blocked 4n x 2b compute with ds_read_b128.
#define C_DIM 8192
#define N_DIM 8192
#define B_DIM 128
#define TN 128            // n-tile per block
#define TB 16             // b-tile per block
#define XW 196            // x_s row stride (>=192 window, mult of 4 for b128 align)
#define WS 132            // w_t row stride (>=128, mult of 4; write stride 1-132 = -131 = 29 mod 32, conflict-free)
#define NROWS (TN + 63)   // 191 K rows feeding this tile

typedef float f4 __attribute__((ext_vector_type(4)));

__global__ __launch_bounds__(256) void cscfc_kernel(
    const float* __restrict__ x,     // (B, C)
    const float* __restrict__ K,     // (C, N)
    const float* __restrict__ bias,  // (N,)
    float* __restrict__ out)         // (B, N)
{
    __shared__ float x_s[TB * XW];   // 12.3 KB: x[b_loc][cc], cc = c - n0, window 192
    __shared__ float w_t[64 * WS];   // 33.0 KB: w_t[f][n_loc] = K[(n0+n_loc+f)%C, n0+n_loc]

    const int t    = threadIdx.x;
    const int lane = t & 63;
    const int rg   = t >> 6;                 // wave id 0..3
    const int n0   = blockIdx.x * TN;
    const int b0   = blockIdx.y * TB;

    // ---- stage x: 16 rows x 192 cols, coalesced ----
    #pragma unroll
    for (int pass = 0; pass < 4; ++pass) {
        const int b_loc = pass * 4 + rg;
        const float* __restrict__ xr = x + (size_t)(b0 + b_loc) * C_DIM;
        #pragma unroll
        for (int k = 0; k < 3; ++k) {
            const int cc = lane + 64 * k;    // 0..191
            x_s[b_loc * XW + cc] = xr[(n0 + cc) & (C_DIM - 1)];
        }
    }

    // ---- stage K band, row-wise coalesced, transposed into w_t[f][n_loc] ----
    // row rr (c = n0+rr): valid n_loc in [max(0,rr-63), min(TN-1,rr)], contiguous <=64 elems
    for (int p = 0; p < 48; ++p) {
        const int rr = p * 4 + rg;           // 0..191 (191 rows used)
        if (rr < NROWS) {
            const int nlo   = (rr - 63 > 0) ? rr - 63 : 0;
            const int nhi   = (rr < TN - 1) ? rr : TN - 1;
            const int n_loc = nlo + lane;
            if (n_loc <= nhi) {
                const int c = (n0 + rr) & (C_DIM - 1);
                const int f = rr - n_loc;    // 0..63
                w_t[f * WS + n_loc] = K[(size_t)c * N_DIM + (n0 + n_loc)];
            }
        }
    }
    __syncthreads();

    // ---- compute: thread owns 4 consecutive n, 2 batches ----
    const int ng     = lane & 31;            // n quad index
    const int n_base = ng * 4;               // n_loc of first owned column
    const int bg     = (lane >> 5) | (rg << 1);   // 0..7
    const int bl0    = bg;                   // batch rows bg and bg+8
    const int bl1    = bg + 8;

    float acc0[4] = {0.f, 0.f, 0.f, 0.f};
    float acc1[4] = {0.f, 0.f, 0.f, 0.f};

    #pragma unroll 4
    for (int f0 = 0; f0 < 64; f0 += 4) {
        // w chunk: 4 rows of w_t, 4 cols each (lane stride 4 words -> conflict-free b128)
        const f4 w0 = *(const f4*)&w_t[(f0 + 0) * WS + n_base];
        const f4 w1 = *(const f4*)&w_t[(f0 + 1) * WS + n_base];
        const f4 w2 = *(const f4*)&w_t[(f0 + 2) * WS + n_base];
        const f4 w3 = *(const f4*)&w_t[(f0 + 3) * WS + n_base];

        const float* xs0 = &x_s[bl0 * XW + n_base + f0];
        const f4 xa = *(const f4*)(xs0);
        const f4 xb = *(const f4*)(xs0 + 4);
        acc0[0] = fmaf(xa.x, w0.x, fmaf(xa.y, w1.x, fmaf(xa.z, w2.x, fmaf(xa.w, w3.x, acc0[0]))));
        acc0[1] = fmaf(xa.y, w0.y, fmaf(xa.z, w1.y, fmaf(xa.w, w2.y, fmaf(xb.x, w3.y, acc0[1]))));
        acc0[2] = fmaf(xa.z, w0.z, fmaf(xa.w, w1.z, fmaf(xb.x, w2.z, fmaf(xb.y, w3.z, acc0[2]))));
        acc0[3] = fmaf(xa.w, w0.w, fmaf(xb.x, w1.w, fmaf(xb.y, w2.w, fmaf(xb.z, w3.w, acc0[3]))));

        const float* xs1 = &x_s[bl1 * XW + n_base + f0];
        const f4 xc = *(const f4*)(xs1);
        const f4 xd = *(const f4*)(xs1 + 4);
        acc1[0] = fmaf(xc.x, w0.x, fmaf(xc.y, w1.x, fmaf(xc.z, w2.x, fmaf(xc.w, w3.x, acc1[0]))));
        acc1[1] = fmaf(xc.y, w0.y, fmaf(xc.z, w1.y, fmaf(xc.w, w2.y, fmaf(xd.x, w3.y, acc1[1]))));
        acc1[2] = fmaf(xc.z, w0.z, fmaf(xc.w, w1.z, fmaf(xd.x, w2.z, fmaf(xd.y, w3.z, acc1[2]))));
        acc1[3] = fmaf(xc.w, w0.w, fmaf(xd.x, w1.w, fmaf(xd.y, w2.w, fmaf(xd.z, w3.w, acc1[3]))));
    }

    // ---- epilogue: bias + coalesced float4 stores ----
    const f4 bv = *(const f4*)(bias + n0 + n_base);
    f4 o0, o1;
    o0.x = acc0[0] + bv.x; o0.y = acc0[1] + bv.y; o0.z = acc0[2] + bv.z; o0.w = acc0[3] + bv.w;
    o1.x = acc1[0] + bv.x; o1.y = acc1[1] + bv.y; o1.z = acc1[2] + bv.z; o1.w = acc1[3] + bv.w;
    *(f4*)(out + (size_t)(b0 + bl0) * N_DIM + n0 + n_base) = o0;
    *(f4*)(out + (size_t)(b0 + bl1) * N_DIM + n0 + n_base) = o1;
}

extern "C" void kernel_launch(void* const* d_in, const int* in_sizes, int n_in,
                              void* d_out, int out_size, void* d_ws, size_t ws_size,
                              hipStream_t stream) {
    const float* x    = (const float*)d_in[0]; // (128, 8192)
    const float* K    = (const float*)d_in[1]; // (8192, 8192)
    const float* bias = (const float*)d_in[2]; // (8192,)
    float* out = (float*)d_out;                // (128, 8192)

    dim3 grid(N_DIM / TN, B_DIM / TB, 1);      // (64, 8) = 512 blocks
    dim3 block(256, 1, 1);
    cscfc_kernel<<<grid, block, 0, stream>>>(x, K, bias, out);
}

// Round 4
// 300.971 us; speedup vs baseline: 1.5048x; 1.0666x over previous
//
#include <hip/hip_runtime.h>

// out[b,n] = sum_{f<64} x[b,(n+f)&8191] * K[(n+f)&8191, n] + bias[n]
// fp32 end-to-end. B=128, C=N=8192, F=64.
//
// R3 postmortem: compute loop fine (~5us LDS floor); K staging was a rolled
// 48-iter scalar load/store loop -> latency-serialized (~25us). R4: stage the
// band via 3 rectangles as unrolled float4 global loads (all in flight before
// any LDS write), predicated scalar transpose-writes into w_t[f][n_loc].
#define C_DIM 8192
#define N_DIM 8192
#define B_DIM 128
#define TN 128            // n-tile per block
#define TB 16             // b-tile per block
#define XW 260            // x_s row stride (256-float staged window + 4 pad; 260%32=4)
#define WS 132            // w_t row stride (132%32=4; transpose-write lane bank-stride 12 -> <=2-way)

typedef float f4 __attribute__((ext_vector_type(4)));

__global__ __launch_bounds__(256) void cscfc_kernel(
    const float* __restrict__ x,     // (B, C)
    const float* __restrict__ K,     // (C, N)
    const float* __restrict__ bias,  // (N,)
    float* __restrict__ out)         // (B, N)
{
    __shared__ float x_s[TB * XW];   // 16.6 KB: x[b_loc][cc], cc = c - n0, window 256
    __shared__ float w_t[64 * WS];   // 33.8 KB: w_t[f][n_loc] = K[(n0+n_loc+f)%C, n0+n_loc]

    const int t    = threadIdx.x;
    const int lane = t & 63;
    const int rg   = t >> 6;
    const int n0   = blockIdx.x * TN;
    const int b0   = blockIdx.y * TB;

    // ---- issue x loads first (waited on earliest) ----
    f4 xq[4];
    #pragma unroll
    for (int i = 0; i < 4; ++i) {
        const int g   = t + 256 * i;          // 0..1023 over 16 rows x 64 quads
        const int row = g >> 6;
        const int col = (g & 63) * 4;
        xq[i] = *(const f4*)&x[(size_t)(b0 + row) * C_DIM + ((n0 + col) & (C_DIM - 1))];
    }

    // ---- issue all K band loads (3 rectangles, unconditional, aligned f4) ----
    // rect1: rows   0..63  x cols   0..63   (g in [0,1024))
    // rect2: rows  64..127 x cols   0..127  (g in [1024,3072))
    // rect3: rows 128..191 x cols  64..127  (g in [3072,4096); row 191 all-invalid)
    f4 kq[16];
    int krow[16], kcol[16];
    #pragma unroll
    for (int i = 0; i < 16; ++i) {
        const int g = t + 256 * i;
        int rr, qc;
        if (g < 1024)      { rr = g >> 4;                    qc = g & 15; }
        else if (g < 3072) { const int h = g - 1024; rr = 64 + (h >> 5); qc = h & 31; }
        else               { const int h = g - 3072; rr = 128 + (h >> 4); qc = 16 + (h & 15); }
        krow[i] = rr;
        kcol[i] = qc * 4;
        const int c = (n0 + rr) & (C_DIM - 1);
        kq[i] = *(const f4*)&K[(size_t)c * N_DIM + n0 + qc * 4];
    }

    // ---- LDS writes: x vectorized, K transpose-scatter (predicated scalar) ----
    #pragma unroll
    for (int i = 0; i < 4; ++i) {
        const int g   = t + 256 * i;
        const int row = g >> 6;
        const int col = (g & 63) * 4;
        *(f4*)&x_s[row * XW + col] = xq[i];
    }
    #pragma unroll
    for (int i = 0; i < 16; ++i) {
        #pragma unroll
        for (int k = 0; k < 4; ++k) {
            const int n_loc = kcol[i] + k;
            const int f     = krow[i] - n_loc;      // valid band: 0 <= f < 64
            if ((unsigned)f < 64u) w_t[f * WS + n_loc] = kq[i][k];
        }
    }
    __syncthreads();

    // ---- compute: thread owns 4 consecutive n, 2 batches (validated in R3) ----
    const int ng     = lane & 31;
    const int n_base = ng * 4;
    const int bg     = (lane >> 5) | (rg << 1);
    const int bl0    = bg;
    const int bl1    = bg + 8;

    float acc0[4] = {0.f, 0.f, 0.f, 0.f};
    float acc1[4] = {0.f, 0.f, 0.f, 0.f};

    #pragma unroll 4
    for (int f0 = 0; f0 < 64; f0 += 4) {
        const f4 w0 = *(const f4*)&w_t[(f0 + 0) * WS + n_base];
        const f4 w1 = *(const f4*)&w_t[(f0 + 1) * WS + n_base];
        const f4 w2 = *(const f4*)&w_t[(f0 + 2) * WS + n_base];
        const f4 w3 = *(const f4*)&w_t[(f0 + 3) * WS + n_base];

        const float* xs0 = &x_s[bl0 * XW + n_base + f0];
        const f4 xa = *(const f4*)(xs0);
        const f4 xb = *(const f4*)(xs0 + 4);
        acc0[0] = fmaf(xa.x, w0.x, fmaf(xa.y, w1.x, fmaf(xa.z, w2.x, fmaf(xa.w, w3.x, acc0[0]))));
        acc0[1] = fmaf(xa.y, w0.y, fmaf(xa.z, w1.y, fmaf(xa.w, w2.y, fmaf(xb.x, w3.y, acc0[1]))));
        acc0[2] = fmaf(xa.z, w0.z, fmaf(xa.w, w1.z, fmaf(xb.x, w2.z, fmaf(xb.y, w3.z, acc0[2]))));
        acc0[3] = fmaf(xa.w, w0.w, fmaf(xb.x, w1.w, fmaf(xb.y, w2.w, fmaf(xb.z, w3.w, acc0[3]))));

        const float* xs1 = &x_s[bl1 * XW + n_base + f0];
        const f4 xc = *(const f4*)(xs1);
        const f4 xd = *(const f4*)(xs1 + 4);
        acc1[0] = fmaf(xc.x, w0.x, fmaf(xc.y, w1.x, fmaf(xc.z, w2.x, fmaf(xc.w, w3.x, acc1[0]))));
        acc1[1] = fmaf(xc.y, w0.y, fmaf(xc.z, w1.y, fmaf(xc.w, w2.y, fmaf(xd.x, w3.y, acc1[1]))));
        acc1[2] = fmaf(xc.z, w0.z, fmaf(xc.w, w1.z, fmaf(xd.x, w2.z, fmaf(xd.y, w3.z, acc1[2]))));
        acc1[3] = fmaf(xc.w, w0.w, fmaf(xd.x, w1.w, fmaf(xd.y, w2.w, fmaf(xd.z, w3.w, acc1[3]))));
    }

    // ---- epilogue: bias + coalesced float4 stores ----
    const f4 bv = *(const f4*)(bias + n0 + n_base);
    f4 o0, o1;
    o0.x = acc0[0] + bv.x; o0.y = acc0[1] + bv.y; o0.z = acc0[2] + bv.z; o0.w = acc0[3] + bv.w;
    o1.x = acc1[0] + bv.x; o1.y = acc1[1] + bv.y; o1.z = acc1[2] + bv.z; o1.w = acc1[3] + bv.w;
    *(f4*)(out + (size_t)(b0 + bl0) * N_DIM + n0 + n_base) = o0;
    *(f4*)(out + (size_t)(b0 + bl1) * N_DIM + n0 + n_base) = o1;
}

extern "C" void kernel_launch(void* const* d_in, const int* in_sizes, int n_in,
                              void* d_out, int out_size, void* d_ws, size_t ws_size,
                              hipStream_t stream) {
    const float* x    = (const float*)d_in[0]; // (128, 8192)
    const float* K    = (const float*)d_in[1]; // (8192, 8192)
    const float* bias = (const float*)d_in[2]; // (8192,)
    float* out = (float*)d_out;                // (128, 8192)

    dim3 grid(N_DIM / TN, B_DIM / TB, 1);      // (64, 8) = 512 blocks
    dim3 block(256, 1, 1);
    cscfc_kernel<<<grid, block, 0, stream>>>(x, K, bias, out);
}

// Round 5
// 299.799 us; speedup vs baseline: 1.5107x; 1.0039x over previous
//
#include <hip/hip_runtime.h>

// out[b,n] = sum_{f<64} x[b,(n+f)&8191] * K[(n+f)&8191, n] + bias[n]
// fp32 end-to-end. B=128, C=N=8192, F=64.
//
// R4 postmortem: ~17us, LDS-pipe floor ~7.2us at 2 waves/SIMD. R5: (1) rolling
// x window in regs (halve x reads), (2) x read direct from global (L1-resident
// 12KB/block) -> x off the LDS pipe, (3) branchless scatter via trash row.
#define C_DIM 8192
#define N_DIM 8192
#define B_DIM 128
#define TN 128            // n-tile per block
#define TB 16             // b-tile per block
#define WS 132            // w_t row stride (scatter-write 4-way conflict, accepted)

typedef float f4 __attribute__((ext_vector_type(4)));

__device__ __forceinline__ f4 ldx(const float* __restrict__ xr, int c) {
    return *(const f4*)&xr[c & (C_DIM - 1)];   // c multiple of 4 -> aligned, no straddle
}

__global__ __launch_bounds__(256) void cscfc_kernel(
    const float* __restrict__ x,     // (B, C)
    const float* __restrict__ K,     // (C, N)
    const float* __restrict__ bias,  // (N,)
    float* __restrict__ out)         // (B, N)
{
    __shared__ float w_t[65 * WS];   // 34.3 KB: w_t[f][n_loc]; row 64 = trash

    const int t    = threadIdx.x;
    const int lane = t & 63;
    const int rg   = t >> 6;
    const int n0   = blockIdx.x * TN;
    const int b0   = blockIdx.y * TB;

    // ---- issue all K band loads (3 rectangles, unconditional, aligned f4) ----
    // rect1: rows   0..63  x cols  0..63 | rect2: rows 64..127 x cols 0..127
    // rect3: rows 128..191 x cols 64..127 (row 191 all-invalid -> trash)
    f4 kq[16];
    int krow[16], kcol[16];
    #pragma unroll
    for (int i = 0; i < 16; ++i) {
        const int g = t + 256 * i;
        int rr, qc;
        if (g < 1024)      { rr = g >> 4;                    qc = g & 15; }
        else if (g < 3072) { const int h = g - 1024; rr = 64 + (h >> 5); qc = h & 31; }
        else               { const int h = g - 3072; rr = 128 + (h >> 4); qc = 16 + (h & 15); }
        krow[i] = rr;
        kcol[i] = qc * 4;
        const int c = (n0 + rr) & (C_DIM - 1);
        kq[i] = *(const f4*)&K[(size_t)c * N_DIM + n0 + qc * 4];
    }

    // ---- branchless transpose-scatter into w_t[f][n_loc], invalid -> row 64 ----
    #pragma unroll
    for (int i = 0; i < 16; ++i) {
        #pragma unroll
        for (int k = 0; k < 4; ++k) {
            const int n_loc = kcol[i] + k;
            const int f     = krow[i] - n_loc;            // band-valid iff 0<=f<64
            const int fc    = ((unsigned)f < 64u) ? f : 64;
            w_t[fc * WS + n_loc] = kq[i][k];
        }
    }
    __syncthreads();

    // ---- compute: thread owns 4 consecutive n, 2 batch rows ----
    const int ng     = lane & 31;
    const int n_base = ng * 4;
    const int bg     = (lane >> 5) | (rg << 1);
    const int bl0    = bg;
    const int bl1    = bg + 8;

    const float* __restrict__ xr0 = x + (size_t)(b0 + bl0) * C_DIM;
    const float* __restrict__ xr1 = x + (size_t)(b0 + bl1) * C_DIM;
    const int cbase = n0 + n_base;                        // multiple of 4

    float acc0[4] = {0.f, 0.f, 0.f, 0.f};
    float acc1[4] = {0.f, 0.f, 0.f, 0.f};

    // rolling window: before chunk f0, xcur=[f0..f0+3], xnxt=[f0+4..f0+7]
    f4 xcur0 = ldx(xr0, cbase);
    f4 xnxt0 = ldx(xr0, cbase + 4);
    f4 xcur1 = ldx(xr1, cbase);
    f4 xnxt1 = ldx(xr1, cbase + 4);

    #pragma unroll
    for (int f0 = 0; f0 < 64; f0 += 4) {
        const f4 w0 = *(const f4*)&w_t[(f0 + 0) * WS + n_base];
        const f4 w1 = *(const f4*)&w_t[(f0 + 1) * WS + n_base];
        const f4 w2 = *(const f4*)&w_t[(f0 + 2) * WS + n_base];
        const f4 w3 = *(const f4*)&w_t[(f0 + 3) * WS + n_base];

        acc0[0] = fmaf(xcur0.x, w0.x, fmaf(xcur0.y, w1.x, fmaf(xcur0.z, w2.x, fmaf(xcur0.w, w3.x, acc0[0]))));
        acc0[1] = fmaf(xcur0.y, w0.y, fmaf(xcur0.z, w1.y, fmaf(xcur0.w, w2.y, fmaf(xnxt0.x, w3.y, acc0[1]))));
        acc0[2] = fmaf(xcur0.z, w0.z, fmaf(xcur0.w, w1.z, fmaf(xnxt0.x, w2.z, fmaf(xnxt0.y, w3.z, acc0[2]))));
        acc0[3] = fmaf(xcur0.w, w0.w, fmaf(xnxt0.x, w1.w, fmaf(xnxt0.y, w2.w, fmaf(xnxt0.z, w3.w, acc0[3]))));

        acc1[0] = fmaf(xcur1.x, w0.x, fmaf(xcur1.y, w1.x, fmaf(xcur1.z, w2.x, fmaf(xcur1.w, w3.x, acc1[0]))));
        acc1[1] = fmaf(xcur1.y, w0.y, fmaf(xcur1.z, w1.y, fmaf(xcur1.w, w2.y, fmaf(xnxt1.x, w3.y, acc1[1]))));
        acc1[2] = fmaf(xcur1.z, w0.z, fmaf(xcur1.w, w1.z, fmaf(xnxt1.x, w2.z, fmaf(xnxt1.y, w3.z, acc1[2]))));
        acc1[3] = fmaf(xcur1.w, w0.w, fmaf(xnxt1.x, w1.w, fmaf(xnxt1.y, w2.w, fmaf(xnxt1.z, w3.w, acc1[3]))));

        if (f0 < 60) {                                   // compile-time under unroll
            xcur0 = xnxt0;  xnxt0 = ldx(xr0, cbase + f0 + 8);
            xcur1 = xnxt1;  xnxt1 = ldx(xr1, cbase + f0 + 8);
        }
    }

    // ---- epilogue: bias + coalesced float4 stores ----
    const f4 bv = *(const f4*)(bias + n0 + n_base);
    f4 o0, o1;
    o0.x = acc0[0] + bv.x; o0.y = acc0[1] + bv.y; o0.z = acc0[2] + bv.z; o0.w = acc0[3] + bv.w;
    o1.x = acc1[0] + bv.x; o1.y = acc1[1] + bv.y; o1.z = acc1[2] + bv.z; o1.w = acc1[3] + bv.w;
    *(f4*)(out + (size_t)(b0 + bl0) * N_DIM + n0 + n_base) = o0;
    *(f4*)(out + (size_t)(b0 + bl1) * N_DIM + n0 + n_base) = o1;
}

extern "C" void kernel_launch(void* const* d_in, const int* in_sizes, int n_in,
                              void* d_out, int out_size, void* d_ws, size_t ws_size,
                              hipStream_t stream) {
    const float* x    = (const float*)d_in[0]; // (128, 8192)
    const float* K    = (const float*)d_in[1]; // (8192, 8192)
    const float* bias = (const float*)d_in[2]; // (8192,)
    float* out = (float*)d_out;                // (128, 8192)

    dim3 grid(N_DIM / TN, B_DIM / TB, 1);      // (64, 8) = 512 blocks
    dim3 block(256, 1, 1);
    cscfc_kernel<<<grid, block, 0, stream>>>(x, K, bias, out);
}